// Round 3
// baseline (1647.485 us; speedup 1.0000x reference)
//
#include <hip/hip_runtime.h>
#include <hip/hip_fp16.h>

#define IN_FEAT 128
#define HEADS 8
#define OUT_FEAT 16
#define HF 128       // HEADS*OUT_FEAT
#define BSHIFT 6     // bucket = dst >> 6  (64 nodes/bucket)
#define BNODES 64
#define NBMAX 1024
#define CHUNK 4096   // edges per bucket_scatter block

// ---------------- K1: h = feat @ W_fc (fp16 out) and post[n][k][h] (fp32) ----
__global__ __launch_bounds__(256) void gemm_post_kernel(
    const float* __restrict__ feat, const float* __restrict__ W_fc,
    const float* __restrict__ W_post, const float* __restrict__ b_post,
    __half* __restrict__ hbuf, float* __restrict__ post, int N)
{
    __shared__ float4 lds4[32 * 32];          // 32 nodes x 128 feats (16 KB)
    float* lds = (float*)lds4;
    const int tid = threadIdx.x;
    const int node_base = blockIdx.x * 32;

    const float4* f4 = (const float4*)feat;
    for (int i = tid; i < 32 * 32; i += 256) {
        int n = i >> 5, k4 = i & 31;
        int gn = node_base + n;
        float4 v = make_float4(0.f, 0.f, 0.f, 0.f);
        if (gn < N) v = f4[gn * 32 + k4];
        lds4[i] = v;
    }
    __syncthreads();

    const int cg = tid & 31, ng = tid >> 5;
    const int n0 = ng * 4;
    float acc[4][4];
#pragma unroll
    for (int i = 0; i < 4; i++) acc[i][0] = acc[i][1] = acc[i][2] = acc[i][3] = 0.f;

    const float4* W4 = (const float4*)W_fc;
#pragma unroll 4
    for (int k = 0; k < 128; ++k) {
        float4 w = W4[k * 32 + cg];
#pragma unroll
        for (int i = 0; i < 4; i++) {
            float f = lds[(n0 + i) * 128 + k];
            acc[i][0] += f * w.x; acc[i][1] += f * w.y;
            acc[i][2] += f * w.z; acc[i][3] += f * w.w;
        }
    }
    __half2* hb2 = (__half2*)hbuf;
#pragma unroll
    for (int i = 0; i < 4; i++) {
        int gn = node_base + n0 + i;
        if (gn < N) {
            union { uint2 u; __half2 h[2]; } pk;
            pk.h[0] = __floats2half2_rn(acc[i][0], acc[i][1]);
            pk.h[1] = __floats2half2_rn(acc[i][2], acc[i][3]);
            *(uint2*)&hb2[gn * 64 + cg * 2] = pk.u;
        }
    }
    __syncthreads();
#pragma unroll
    for (int i = 0; i < 4; i++)
        lds4[(n0 + i) * 32 + cg] = make_float4(acc[i][0], acc[i][1], acc[i][2], acc[i][3]);
    __syncthreads();

    {
        int n = tid >> 3, h = tid & 7;
        float p0 = b_post[0], p1 = b_post[1], p2 = b_post[2], p3 = b_post[3];
#pragma unroll
        for (int f = 0; f < 16; ++f) {
            float v = lds[n * 128 + h * 16 + f];
            p0 += v * W_post[f * 4 + 0];
            p1 += v * W_post[f * 4 + 1];
            p2 += v * W_post[f * 4 + 2];
            p3 += v * W_post[f * 4 + 3];
        }
        int gn = node_base + n;
        if (gn < N) {
            // layout post[n][k][h], k: 0=loc_l 1=loc_r 2=lsl 3=lsr
            post[gn * 32 + 0 * 8 + h] = p0;
            post[gn * 32 + 1 * 8 + h] = p1;
            post[gn * 32 + 2 * 8 + h] = p2;
            post[gn * 32 + 3 * 8 + h] = p3;
        }
    }
}

// ---------------- K2: bucket histogram (bucket = dst>>6) ----------------
__global__ __launch_bounds__(256) void bucket_hist_kernel(
    const int* __restrict__ dst, int* __restrict__ bucket_tot, int E, int nb)
{
    __shared__ int cnt[NBMAX];
    const int tid = threadIdx.x;
    for (int i = tid; i < nb; i += 256) cnt[i] = 0;
    __syncthreads();
    const int stride = gridDim.x * 256;
    for (int g = blockIdx.x * 256 + tid; g < E; g += stride)
        atomicAdd(&cnt[dst[g] >> BSHIFT], 1);
    __syncthreads();
    for (int i = tid; i < nb; i += 256) {
        int c = cnt[i];
        if (c) atomicAdd(&bucket_tot[i], c);
    }
}

// ---------------- K3: scan bucket totals -> base, cursor ----------------
__global__ __launch_bounds__(256) void bucket_scan_kernel(
    const int* __restrict__ bucket_tot, int* __restrict__ bucket_base,
    int* __restrict__ bucket_cursor, int nb, int E)
{
    __shared__ int sd[256];
    const int tid = threadIdx.x;
    int v[4]; int s = 0;
#pragma unroll
    for (int k = 0; k < 4; ++k) {
        int i = tid * 4 + k;
        v[k] = (i < nb) ? bucket_tot[i] : 0;
        s += v[k];
    }
    sd[tid] = s;
    __syncthreads();
    for (int off = 1; off < 256; off <<= 1) {
        int t = (tid >= off) ? sd[tid - off] : 0;
        __syncthreads();
        sd[tid] += t;
        __syncthreads();
    }
    int excl = sd[tid] - s;
#pragma unroll
    for (int k = 0; k < 4; ++k) {
        int i = tid * 4 + k;
        if (i < nb) { bucket_base[i] = excl; bucket_cursor[i] = excl; }
        excl += v[k];
    }
    if (tid == 0) bucket_base[nb] = E;
}

// ---------------- K4: bin edges into bucket-contiguous record arrays --------
__global__ __launch_bounds__(256) void bucket_scatter_kernel(
    const int* __restrict__ src, const int* __restrict__ dst,
    int* __restrict__ bucket_cursor, uint2* __restrict__ recs, int E, int nb)
{
    __shared__ int cnt[NBMAX];
    __shared__ int base[NBMAX];
    const int tid = threadIdx.x;
    for (int i = tid; i < nb; i += 256) cnt[i] = 0;
    __syncthreads();
    const int e0 = blockIdx.x * CHUNK;
    const int e1 = min(e0 + CHUNK, E);
    for (int e = e0 + tid; e < e1; e += 256)
        atomicAdd(&cnt[dst[e] >> BSHIFT], 1);
    __syncthreads();
    for (int i = tid; i < nb; i += 256) {
        int c = cnt[i];
        base[i] = c ? atomicAdd(&bucket_cursor[i], c) : 0;
        cnt[i] = 0;   // reuse as local cursor
    }
    __syncthreads();
    for (int e = e0 + tid; e < e1; e += 256) {
        int d = dst[e];
        int b = d >> BSHIFT;
        int slot = base[b] + atomicAdd(&cnt[b], 1);
        recs[slot] = make_uint2((unsigned)e,
                                ((unsigned)src[e] << BSHIFT) | (unsigned)(d & (BNODES - 1)));
    }
}

// ---------------- K5: fused per-bucket score + aggregation ----------------
// One block (4 waves) per bucket of 64 dst nodes. Whole bucket's accumulator
// state lives in LDS: acc[64][128] + dsum[64][8]. Edges streamed from the
// bucket's recs region in ARBITRARY order; accumulation via LDS f32 atomics
// (lane -> acc[dl*128 + 2*lane] : consecutive addresses, conflict-free).
// Eliminates the CSR build pass entirely.
__global__ __launch_bounds__(256) void bucket_agg_kernel(
    const uint2* __restrict__ recs, const int* __restrict__ bucket_base,
    const float* __restrict__ post, const float* __restrict__ eps,
    const __half* __restrict__ hbuf, const float* __restrict__ bias,
    float* __restrict__ out, int N)
{
    __shared__ float acc[BNODES * 128];   // 32 KB
    __shared__ float dsum[BNODES * 8];    // 2 KB
    __shared__ float s_lr[BNODES * 8];    // loc_r[node][h], 2 KB
    __shared__ float s_ls[BNODES * 8];    // lsr[node][h],  2 KB

    const int b = blockIdx.x, tid = threadIdx.x;
    const int node_lo = b << BSHIFT;
    const int rlo = bucket_base[b], rhi = bucket_base[b + 1];
    const int wave = tid >> 6, lane = tid & 63;
    const int h = lane >> 3;

    for (int i = tid; i < BNODES * 128; i += 256) acc[i] = 0.f;
    for (int i = tid; i < BNODES * 8; i += 256) {
        dsum[i] = 0.f;
        int n = i >> 3, hh = i & 7;
        int gn = node_lo + n;
        float lr = 0.f, ls = 0.f;
        if (gn < N) { lr = post[gn * 32 + 8 + hh]; ls = post[gn * 32 + 24 + hh]; }
        s_lr[i] = lr; s_ls[i] = ls;
    }
    __syncthreads();

    const int T = rhi - rlo;
    const int T4 = T & ~15;

    // main loop: 4 edges per wave per iteration (16 per block-iteration)
    for (int c = wave * 4; c < T4; c += 16) {
        const int r0 = rlo + c;
        uint2 rec[4];
#pragma unroll
        for (int i = 0; i < 4; i++) rec[i] = recs[r0 + i];
        float ex[4]; float2 hv[4]; int dl[4];
#pragma unroll
        for (int i = 0; i < 4; i++) {
            int e = (int)rec[i].x;
            dl[i] = (int)(rec[i].y & (BNODES - 1u));
            int s = (int)(rec[i].y >> BSHIFT);
            float ll = post[s * 32 + h];
            float sl = post[s * 32 + 16 + h];
            float ep = eps[(size_t)e * 8 + h];
            hv[i] = __half22float2(((const __half2*)(hbuf + (size_t)s * HF))[lane]);
            ex[i] = __expf((ll + s_lr[dl[i] * 8 + h]) +
                           __expf(sl + s_ls[dl[i] * 8 + h]) * ep);
        }
#pragma unroll
        for (int i = 0; i < 4; i++) {
            atomicAdd(&acc[dl[i] * 128 + 2 * lane],     ex[i] * hv[i].x);
            atomicAdd(&acc[dl[i] * 128 + 2 * lane + 1], ex[i] * hv[i].y);
            if ((lane & 7) == 0) atomicAdd(&dsum[dl[i] * 8 + h], ex[i]);
        }
    }
    // tail
    for (int c = T4 + wave; c < T; c += 4) {
        uint2 rec = recs[rlo + c];
        int e = (int)rec.x;
        int dl = (int)(rec.y & (BNODES - 1u));
        int s = (int)(rec.y >> BSHIFT);
        float ll = post[s * 32 + h];
        float sl = post[s * 32 + 16 + h];
        float ep = eps[(size_t)e * 8 + h];
        float2 hv = __half22float2(((const __half2*)(hbuf + (size_t)s * HF))[lane]);
        float ex = __expf((ll + s_lr[dl * 8 + h]) +
                          __expf(sl + s_ls[dl * 8 + h]) * ep);
        atomicAdd(&acc[dl * 128 + 2 * lane],     ex * hv.x);
        atomicAdd(&acc[dl * 128 + 2 * lane + 1], ex * hv.y);
        if ((lane & 7) == 0) atomicAdd(&dsum[dl * 8 + h], ex);
    }
    __syncthreads();

    // invert denominators
    for (int i = tid; i < BNODES * 8; i += 256) {
        float dv = dsum[i];
        dsum[i] = (dv > 0.f) ? 1.f / dv : 0.f;
    }
    __syncthreads();

    // write out[n][h][f] = acc * inv + bias
    const float2* acc2 = (const float2*)acc;
    const float2* bias2 = (const float2*)bias;
    float2* out2 = (float2*)out;
    for (int i = tid; i < BNODES * 64; i += 256) {
        int n = i >> 6, idx2 = i & 63;
        int gn = node_lo + n;
        if (gn < N) {
            float inv = dsum[n * 8 + (idx2 >> 3)];
            float2 A = acc2[i];
            float2 bv = bias2[idx2];
            out2[(size_t)gn * 64 + idx2] = make_float2(A.x * inv + bv.x,
                                                       A.y * inv + bv.y);
        }
    }
}

extern "C" void kernel_launch(void* const* d_in, const int* in_sizes, int n_in,
                              void* d_out, int out_size, void* d_ws, size_t ws_size,
                              hipStream_t stream)
{
    const float* feat   = (const float*)d_in[0];
    const int*   src    = (const int*)d_in[1];
    const int*   dst    = (const int*)d_in[2];
    const float* eps    = (const float*)d_in[3];
    const float* W_fc   = (const float*)d_in[4];
    const float* W_post = (const float*)d_in[5];
    const float* b_post = (const float*)d_in[6];
    const float* bias   = (const float*)d_in[7];
    float* out = (float*)d_out;

    const int N = in_sizes[0] / IN_FEAT;         // 50000
    const int E = in_sizes[1];                   // 1600000
    const int nb = (N + BNODES - 1) >> BSHIFT;   // 782 buckets

    // workspace layout (256B-aligned segments), total ~33 MB
    char* p = (char*)d_ws;
    auto alloc = [&](size_t bytes) {
        char* r = p;
        p += (bytes + 255) & ~size_t(255);
        return r;
    };
    __half* hbuf    = (__half*)alloc((size_t)N * HF * 2);     // 12.8 MB fp16
    float*  post    = (float*)alloc((size_t)N * 32 * 4);      // 6.4 MB
    int*    bucket_tot    = (int*)alloc((size_t)(NBMAX + 1) * 4);
    int*    bucket_base   = (int*)alloc((size_t)(NBMAX + 1) * 4);
    int*    bucket_cursor = (int*)alloc((size_t)(NBMAX + 1) * 4);
    uint2*  recs    = (uint2*)alloc((size_t)E * 8);           // 12.8 MB

    hipMemsetAsync(bucket_tot, 0, (size_t)nb * 4, stream);

    gemm_post_kernel<<<(N + 31) / 32, 256, 0, stream>>>(feat, W_fc, W_post, b_post,
                                                        hbuf, post, N);
    bucket_hist_kernel<<<512, 256, 0, stream>>>(dst, bucket_tot, E, nb);
    bucket_scan_kernel<<<1, 256, 0, stream>>>(bucket_tot, bucket_base,
                                              bucket_cursor, nb, E);
    bucket_scatter_kernel<<<(E + CHUNK - 1) / CHUNK, 256, 0, stream>>>(
        src, dst, bucket_cursor, recs, E, nb);
    bucket_agg_kernel<<<nb, 256, 0, stream>>>(recs, bucket_base, post, eps, hbuf,
                                              bias, out, N);
}

// Round 4
// 371.671 us; speedup vs baseline: 4.4326x; 4.4326x over previous
//
#include <hip/hip_runtime.h>
#include <hip/hip_fp16.h>

#define IN_FEAT 128
#define HEADS 8
#define OUT_FEAT 16
#define HF 128       // HEADS*OUT_FEAT
#define BSHIFT 6     // bucket = dst >> 6  (64 nodes/bucket)
#define BNODES 64
#define NBMAX 1024
#define CHUNK 4096   // edges per scatter block
#define PCAP 4096    // perm capacity per chunk in fused agg

// ---------------- K1: bucket histogram (bucket = dst>>6) ----------------
__global__ __launch_bounds__(256) void bucket_hist_kernel(
    const int* __restrict__ dst, int* __restrict__ bucket_tot, int E, int nb)
{
    __shared__ int cnt[NBMAX];
    const int tid = threadIdx.x;
    for (int i = tid; i < nb; i += 256) cnt[i] = 0;
    __syncthreads();
    const int stride = gridDim.x * 256;
    for (int g = blockIdx.x * 256 + tid; g < E; g += stride)
        atomicAdd(&cnt[dst[g] >> BSHIFT], 1);
    __syncthreads();
    for (int i = tid; i < nb; i += 256) {
        int c = cnt[i];
        if (c) atomicAdd(&bucket_tot[i], c);
    }
}

// ---------------- K2: scan bucket totals -> base, cursor ----------------
__global__ __launch_bounds__(256) void bucket_scan_kernel(
    const int* __restrict__ bucket_tot, int* __restrict__ bucket_base,
    int* __restrict__ bucket_cursor, int nb, int E)
{
    __shared__ int sd[256];
    const int tid = threadIdx.x;
    int v[4]; int s = 0;
#pragma unroll
    for (int k = 0; k < 4; ++k) {
        int i = tid * 4 + k;
        v[k] = (i < nb) ? bucket_tot[i] : 0;
        s += v[k];
    }
    sd[tid] = s;
    __syncthreads();
    for (int off = 1; off < 256; off <<= 1) {
        int t = (tid >= off) ? sd[tid - off] : 0;
        __syncthreads();
        sd[tid] += t;
        __syncthreads();
    }
    int excl = sd[tid] - s;
#pragma unroll
    for (int k = 0; k < 4; ++k) {
        int i = tid * 4 + k;
        if (i < nb) { bucket_base[i] = excl; bucket_cursor[i] = excl; }
        excl += v[k];
    }
    if (tid == 0) bucket_base[nb] = E;
}

// ---------------- K3 (fat): scatter (blocks < SB) || gemm+post (blocks >= SB)
// scatter and gemm touch disjoint data -> co-run to hide scatter under gemm.
__global__ __launch_bounds__(256) void gemm_scatter_kernel(
    const float* __restrict__ feat, const float* __restrict__ W_fc,
    const float* __restrict__ W_post, const float* __restrict__ b_post,
    __half* __restrict__ hbuf, float* __restrict__ post, int N,
    const int* __restrict__ src, const int* __restrict__ dst,
    int* __restrict__ bucket_cursor, uint2* __restrict__ recs, int E, int nb,
    int SB)
{
    __shared__ float4 lds4[32 * 32];          // 16 KB, aliased by both paths
    const int tid = threadIdx.x;

    if (blockIdx.x < SB) {
        // ---------- scatter path ----------
        int* cnt  = (int*)lds4;               // [NBMAX]
        int* base = cnt + NBMAX;              // [NBMAX]
        for (int i = tid; i < nb; i += 256) cnt[i] = 0;
        __syncthreads();
        const int e0 = blockIdx.x * CHUNK;
        const int e1 = min(e0 + CHUNK, E);
        for (int e = e0 + tid; e < e1; e += 256)
            atomicAdd(&cnt[dst[e] >> BSHIFT], 1);
        __syncthreads();
        for (int i = tid; i < nb; i += 256) {
            int c = cnt[i];
            base[i] = c ? atomicAdd(&bucket_cursor[i], c) : 0;
            cnt[i] = 0;   // reuse as local cursor
        }
        __syncthreads();
        for (int e = e0 + tid; e < e1; e += 256) {
            int d = dst[e];
            int b = d >> BSHIFT;
            int slot = base[b] + atomicAdd(&cnt[b], 1);
            recs[slot] = make_uint2((unsigned)e,
                                    ((unsigned)src[e] << BSHIFT) | (unsigned)(d & (BNODES - 1)));
        }
        return;
    }

    // ---------- gemm + post path ----------
    float* lds = (float*)lds4;
    const int node_base = (blockIdx.x - SB) * 32;

    const float4* f4 = (const float4*)feat;
    for (int i = tid; i < 32 * 32; i += 256) {
        int n = i >> 5, k4 = i & 31;
        int gn = node_base + n;
        float4 v = make_float4(0.f, 0.f, 0.f, 0.f);
        if (gn < N) v = f4[gn * 32 + k4];
        lds4[i] = v;
    }
    __syncthreads();

    const int cg = tid & 31, ng = tid >> 5;
    const int n0 = ng * 4;
    float acc[4][4];
#pragma unroll
    for (int i = 0; i < 4; i++) acc[i][0] = acc[i][1] = acc[i][2] = acc[i][3] = 0.f;

    const float4* W4 = (const float4*)W_fc;
#pragma unroll 4
    for (int k = 0; k < 128; ++k) {
        float4 w = W4[k * 32 + cg];
#pragma unroll
        for (int i = 0; i < 4; i++) {
            float f = lds[(n0 + i) * 128 + k];
            acc[i][0] += f * w.x; acc[i][1] += f * w.y;
            acc[i][2] += f * w.z; acc[i][3] += f * w.w;
        }
    }
    __half2* hb2 = (__half2*)hbuf;
#pragma unroll
    for (int i = 0; i < 4; i++) {
        int gn = node_base + n0 + i;
        if (gn < N) {
            union { uint2 u; __half2 h[2]; } pk;
            pk.h[0] = __floats2half2_rn(acc[i][0], acc[i][1]);
            pk.h[1] = __floats2half2_rn(acc[i][2], acc[i][3]);
            *(uint2*)&hb2[gn * 64 + cg * 2] = pk.u;
        }
    }
    __syncthreads();
#pragma unroll
    for (int i = 0; i < 4; i++)
        lds4[(n0 + i) * 32 + cg] = make_float4(acc[i][0], acc[i][1], acc[i][2], acc[i][3]);
    __syncthreads();

    {
        int n = tid >> 3, h = tid & 7;
        float p0 = b_post[0], p1 = b_post[1], p2 = b_post[2], p3 = b_post[3];
#pragma unroll
        for (int f = 0; f < 16; ++f) {
            float v = lds[n * 128 + h * 16 + f];
            p0 += v * W_post[f * 4 + 0];
            p1 += v * W_post[f * 4 + 1];
            p2 += v * W_post[f * 4 + 2];
            p3 += v * W_post[f * 4 + 3];
        }
        int gn = node_base + n;
        if (gn < N) {
            // layout post[n][k][h], k: 0=loc_l 1=loc_r 2=lsl 3=lsr
            post[gn * 32 + 0 * 8 + h] = p0;
            post[gn * 32 + 1 * 8 + h] = p1;
            post[gn * 32 + 2 * 8 + h] = p2;
            post[gn * 32 + 3 * 8 + h] = p3;
        }
    }
}

// ---------------- K4: fused permute + score + aggregation ----------------
// One 512-thread block (8 waves) per bucket of 64 dst nodes.
// Phase A: build per-node permutation of the bucket's recs in LDS (u16),
//          via LDS hist + wave scan + LDS-atomic slot assignment.
// Phase B: proven round-2 inner loop — one wave per node, register
//          accumulators, shfl broadcast, no LDS atomics in hot loop.
__global__ __launch_bounds__(512) void agg_kernel(
    const uint2* __restrict__ recs, const int* __restrict__ bucket_base,
    const float* __restrict__ post, const float* __restrict__ eps,
    const __half* __restrict__ hbuf, const float* __restrict__ bias,
    float* __restrict__ out, int N)
{
    __shared__ unsigned short perm[PCAP];   // 8 KB
    __shared__ int ncnt[BNODES];
    __shared__ int offs[BNODES];
    __shared__ int cur[BNODES];

    const int b = blockIdx.x, tid = threadIdx.x;
    const int node_lo = b << BSHIFT;
    const int rlo = bucket_base[b], rhi = bucket_base[b + 1];
    const int T = rhi - rlo;
    const int w = tid >> 6, lane = tid & 63;
    const int j = lane >> 3, hh = lane & 7;

    float2 acc[8];
    float dsum[8];
#pragma unroll
    for (int i = 0; i < 8; i++) { acc[i] = make_float2(0.f, 0.f); dsum[i] = 0.f; }

    for (int cb = 0; cb < T; cb += PCAP) {
        const int Tc = min(PCAP, T - cb);
        const uint2* rbase = recs + rlo + cb;

        // A1: zero node hist
        if (tid < BNODES) ncnt[tid] = 0;
        __syncthreads();
        // A2: histogram chunk by local node
        for (int r = tid; r < Tc; r += 512)
            atomicAdd(&ncnt[rbase[r].y & (BNODES - 1u)], 1);
        __syncthreads();
        // A3: exclusive scan (wave 0)
        if (tid < 64) {
            int v = ncnt[tid];
            int s = v;
#pragma unroll
            for (int off = 1; off < 64; off <<= 1) {
                int t = __shfl_up(s, off, 64);
                if (lane >= off) s += t;
            }
            offs[tid] = s - v;
            cur[tid]  = s - v;
        }
        __syncthreads();
        // A4: scatter record indices into perm (node-sorted order)
        for (int r = tid; r < Tc; r += 512) {
            int dl = (int)(rbase[r].y & (BNODES - 1u));
            int slot = atomicAdd(&cur[dl], 1);
            perm[slot] = (unsigned short)r;
        }
        __syncthreads();

        // B: wave w handles nodes w, w+8, ..., w+56
#pragma unroll
        for (int i = 0; i < 8; i++) {
            const int n = (i << 3) | w;
            const int cn = ncnt[n];
            if (cn == 0) continue;
            const int o = offs[n];
            const int gn = node_lo + n;
            float dlr = 0.f, dls = 0.f;
            if (gn < N) { dlr = post[gn * 32 + 8 + hh]; dls = post[gn * 32 + 24 + hh]; }

            int c = 0;
            for (; c + 8 <= cn; c += 8) {
                int pidx = perm[o + c + j];
                uint2 rec = rbase[pidx];
                int e = (int)rec.x, s = (int)(rec.y >> BSHIFT);
                float ll = post[s * 32 + hh];
                float sl = post[s * 32 + 16 + hh];
                float ep = eps[(size_t)e * 8 + hh];
                float ex = __expf((ll + dlr) + __expf(sl + dls) * ep);
#pragma unroll
                for (int jj = 0; jj < 8; ++jj) {
                    float a = __shfl(ex, jj * 8 + j, 64);
                    int  sj = __shfl(s, jj * 8, 64);
                    float2 hv = __half22float2(((const __half2*)(hbuf + (size_t)sj * HF))[lane]);
                    acc[i].x += a * hv.x;
                    acc[i].y += a * hv.y;
                    dsum[i] += a;
                }
            }
            if (c < cn) {
                int jc = cn - c;
                int pidx = perm[o + c + min(j, jc - 1)];
                uint2 rec = rbase[pidx];
                int e = (int)rec.x, s = (int)(rec.y >> BSHIFT);
                float ll = post[s * 32 + hh];
                float sl = post[s * 32 + 16 + hh];
                float ep = eps[(size_t)e * 8 + hh];
                float ex = (j < jc) ? __expf((ll + dlr) + __expf(sl + dls) * ep) : 0.f;
                for (int jj = 0; jj < jc; ++jj) {
                    float a = __shfl(ex, jj * 8 + j, 64);
                    int  sj = __shfl(s, jj * 8, 64);
                    float2 hv = __half22float2(((const __half2*)(hbuf + (size_t)sj * HF))[lane]);
                    acc[i].x += a * hv.x;
                    acc[i].y += a * hv.y;
                    dsum[i] += a;
                }
            }
        }
        __syncthreads();
    }

    const float2 bv = ((const float2*)bias)[lane];
    float2* out2 = (float2*)out;
#pragma unroll
    for (int i = 0; i < 8; i++) {
        int n = (i << 3) | w;
        int gn = node_lo + n;
        if (gn < N) {
            float inv = (dsum[i] > 0.f) ? 1.f / dsum[i] : 0.f;
            out2[(size_t)gn * 64 + lane] = make_float2(acc[i].x * inv + bv.x,
                                                       acc[i].y * inv + bv.y);
        }
    }
}

extern "C" void kernel_launch(void* const* d_in, const int* in_sizes, int n_in,
                              void* d_out, int out_size, void* d_ws, size_t ws_size,
                              hipStream_t stream)
{
    const float* feat   = (const float*)d_in[0];
    const int*   src    = (const int*)d_in[1];
    const int*   dst    = (const int*)d_in[2];
    const float* eps    = (const float*)d_in[3];
    const float* W_fc   = (const float*)d_in[4];
    const float* W_post = (const float*)d_in[5];
    const float* b_post = (const float*)d_in[6];
    const float* bias   = (const float*)d_in[7];
    float* out = (float*)d_out;

    const int N = in_sizes[0] / IN_FEAT;         // 50000
    const int E = in_sizes[1];                   // 1600000
    const int nb = (N + BNODES - 1) >> BSHIFT;   // 782 buckets
    const int SB = (E + CHUNK - 1) / CHUNK;      // scatter blocks
    const int GB = (N + 31) / 32;                // gemm blocks

    // workspace layout (256B-aligned segments), total ~33 MB
    char* p = (char*)d_ws;
    auto alloc = [&](size_t bytes) {
        char* r = p;
        p += (bytes + 255) & ~size_t(255);
        return r;
    };
    __half* hbuf    = (__half*)alloc((size_t)N * HF * 2);     // 12.8 MB fp16
    float*  post    = (float*)alloc((size_t)N * 32 * 4);      // 6.4 MB
    int*    bucket_tot    = (int*)alloc((size_t)(NBMAX + 1) * 4);
    int*    bucket_base   = (int*)alloc((size_t)(NBMAX + 1) * 4);
    int*    bucket_cursor = (int*)alloc((size_t)(NBMAX + 1) * 4);
    uint2*  recs    = (uint2*)alloc((size_t)E * 8);           // 12.8 MB

    hipMemsetAsync(bucket_tot, 0, (size_t)nb * 4, stream);

    bucket_hist_kernel<<<512, 256, 0, stream>>>(dst, bucket_tot, E, nb);
    bucket_scan_kernel<<<1, 256, 0, stream>>>(bucket_tot, bucket_base,
                                              bucket_cursor, nb, E);
    gemm_scatter_kernel<<<SB + GB, 256, 0, stream>>>(
        feat, W_fc, W_post, b_post, hbuf, post, N,
        src, dst, bucket_cursor, recs, E, nb, SB);
    agg_kernel<<<nb, 512, 0, stream>>>(recs, bucket_base, post, eps, hbuf,
                                       bias, out, N);
}

// Round 5
// 310.783 us; speedup vs baseline: 5.3011x; 1.1959x over previous
//
#include <hip/hip_runtime.h>
#include <hip/hip_fp16.h>

#define IN_FEAT 128
#define HEADS 8
#define OUT_FEAT 16
#define HF 128       // HEADS*OUT_FEAT
#define BSHIFT 6     // bucket = dst >> 6  (64 nodes/bucket)
#define BNODES 64
#define NBMAX 1024
#define CHUNK 4096   // edges per scatter block

// ---------------- K1: bucket histogram (bucket = dst>>6) ----------------
__global__ __launch_bounds__(256) void bucket_hist_kernel(
    const int* __restrict__ dst, int* __restrict__ bucket_tot, int E, int nb)
{
    __shared__ int cnt[NBMAX];
    const int tid = threadIdx.x;
    for (int i = tid; i < nb; i += 256) cnt[i] = 0;
    __syncthreads();
    const int stride = gridDim.x * 256;
    for (int g = blockIdx.x * 256 + tid; g < E; g += stride)
        atomicAdd(&cnt[dst[g] >> BSHIFT], 1);
    __syncthreads();
    for (int i = tid; i < nb; i += 256) {
        int c = cnt[i];
        if (c) atomicAdd(&bucket_tot[i], c);
    }
}

// ---------------- K2: scan bucket totals -> base, cursor ----------------
__global__ __launch_bounds__(256) void bucket_scan_kernel(
    const int* __restrict__ bucket_tot, int* __restrict__ bucket_base,
    int* __restrict__ bucket_cursor, int nb, int E)
{
    __shared__ int sd[256];
    const int tid = threadIdx.x;
    int v[4]; int s = 0;
#pragma unroll
    for (int k = 0; k < 4; ++k) {
        int i = tid * 4 + k;
        v[k] = (i < nb) ? bucket_tot[i] : 0;
        s += v[k];
    }
    sd[tid] = s;
    __syncthreads();
    for (int off = 1; off < 256; off <<= 1) {
        int t = (tid >= off) ? sd[tid - off] : 0;
        __syncthreads();
        sd[tid] += t;
        __syncthreads();
    }
    int excl = sd[tid] - s;
#pragma unroll
    for (int k = 0; k < 4; ++k) {
        int i = tid * 4 + k;
        if (i < nb) { bucket_base[i] = excl; bucket_cursor[i] = excl; }
        excl += v[k];
    }
    if (tid == 0) bucket_base[nb] = E;
}

// ---------------- K3 (fat): scatter (blocks < SB) || gemm+post (blocks >= SB)
// scatter and gemm touch disjoint data -> co-run to hide scatter under gemm.
__global__ __launch_bounds__(256) void gemm_scatter_kernel(
    const float* __restrict__ feat, const float* __restrict__ W_fc,
    const float* __restrict__ W_post, const float* __restrict__ b_post,
    __half* __restrict__ hbuf, float* __restrict__ post, int N,
    const int* __restrict__ src, const int* __restrict__ dst,
    int* __restrict__ bucket_cursor, uint2* __restrict__ recs, int E, int nb,
    int SB)
{
    __shared__ float4 lds4[32 * 32];          // 16 KB, aliased by both paths
    const int tid = threadIdx.x;

    if (blockIdx.x < SB) {
        // ---------- scatter path ----------
        int* cnt  = (int*)lds4;               // [NBMAX]
        int* base = cnt + NBMAX;              // [NBMAX]
        for (int i = tid; i < nb; i += 256) cnt[i] = 0;
        __syncthreads();
        const int e0 = blockIdx.x * CHUNK;
        const int e1 = min(e0 + CHUNK, E);
        for (int e = e0 + tid; e < e1; e += 256)
            atomicAdd(&cnt[dst[e] >> BSHIFT], 1);
        __syncthreads();
        for (int i = tid; i < nb; i += 256) {
            int c = cnt[i];
            base[i] = c ? atomicAdd(&bucket_cursor[i], c) : 0;
            cnt[i] = 0;   // reuse as local cursor
        }
        __syncthreads();
        for (int e = e0 + tid; e < e1; e += 256) {
            int d = dst[e];
            int b = d >> BSHIFT;
            int slot = base[b] + atomicAdd(&cnt[b], 1);
            recs[slot] = make_uint2((unsigned)e,
                                    ((unsigned)src[e] << BSHIFT) | (unsigned)(d & (BNODES - 1)));
        }
        return;
    }

    // ---------- gemm + post path ----------
    float* lds = (float*)lds4;
    const int node_base = (blockIdx.x - SB) * 32;

    const float4* f4 = (const float4*)feat;
    for (int i = tid; i < 32 * 32; i += 256) {
        int n = i >> 5, k4 = i & 31;
        int gn = node_base + n;
        float4 v = make_float4(0.f, 0.f, 0.f, 0.f);
        if (gn < N) v = f4[gn * 32 + k4];
        lds4[i] = v;
    }
    __syncthreads();

    const int cg = tid & 31, ng = tid >> 5;
    const int n0 = ng * 4;
    float acc[4][4];
#pragma unroll
    for (int i = 0; i < 4; i++) acc[i][0] = acc[i][1] = acc[i][2] = acc[i][3] = 0.f;

    const float4* W4 = (const float4*)W_fc;
#pragma unroll 4
    for (int k = 0; k < 128; ++k) {
        float4 w = W4[k * 32 + cg];
#pragma unroll
        for (int i = 0; i < 4; i++) {
            float f = lds[(n0 + i) * 128 + k];
            acc[i][0] += f * w.x; acc[i][1] += f * w.y;
            acc[i][2] += f * w.z; acc[i][3] += f * w.w;
        }
    }
    __half2* hb2 = (__half2*)hbuf;
#pragma unroll
    for (int i = 0; i < 4; i++) {
        int gn = node_base + n0 + i;
        if (gn < N) {
            union { uint2 u; __half2 h[2]; } pk;
            pk.h[0] = __floats2half2_rn(acc[i][0], acc[i][1]);
            pk.h[1] = __floats2half2_rn(acc[i][2], acc[i][3]);
            *(uint2*)&hb2[gn * 64 + cg * 2] = pk.u;
        }
    }
    __syncthreads();
#pragma unroll
    for (int i = 0; i < 4; i++)
        lds4[(n0 + i) * 32 + cg] = make_float4(acc[i][0], acc[i][1], acc[i][2], acc[i][3]);
    __syncthreads();

    {
        int n = tid >> 3, h = tid & 7;
        float p0 = b_post[0], p1 = b_post[1], p2 = b_post[2], p3 = b_post[3];
#pragma unroll
        for (int f = 0; f < 16; ++f) {
            float v = lds[n * 128 + h * 16 + f];
            p0 += v * W_post[f * 4 + 0];
            p1 += v * W_post[f * 4 + 1];
            p2 += v * W_post[f * 4 + 2];
            p3 += v * W_post[f * 4 + 3];
        }
        int gn = node_base + n;
        if (gn < N) {
            // layout post[n][k][h], k: 0=loc_l 1=loc_r 2=lsl 3=lsr
            post[gn * 32 + 0 * 8 + h] = p0;
            post[gn * 32 + 1 * 8 + h] = p1;
            post[gn * 32 + 2 * 8 + h] = p2;
            post[gn * 32 + 3 * 8 + h] = p3;
        }
    }
}

// ---------------- K4: per-bucket CSR build (records -> slot order) ----------
// One block per bucket (64 nodes). Local node hist -> scan -> offsets; then
// csr[slot] = (edge, src). Single-writer bucket region.
__global__ __launch_bounds__(256) void bucket_csr_kernel(
    const uint2* __restrict__ recs, const int* __restrict__ bucket_base,
    int* __restrict__ offsets, uint2* __restrict__ csr, int N, int E)
{
    __shared__ int ncnt[BNODES];
    __shared__ int snc[BNODES];
    const int b = blockIdx.x, tid = threadIdx.x;
    const int node_lo = b << BSHIFT;
    const int rlo = bucket_base[b], rhi = bucket_base[b + 1];
    const int gn = node_lo + tid;

    if (tid < BNODES) ncnt[tid] = 0;
    __syncthreads();
    for (int r = rlo + tid; r < rhi; r += 256)
        atomicAdd(&ncnt[recs[r].y & (BNODES - 1u)], 1);
    __syncthreads();
    if (tid < BNODES) snc[tid] = ncnt[tid];
    __syncthreads();
    for (int off = 1; off < BNODES; off <<= 1) {
        int t = (tid < BNODES && tid >= off) ? snc[tid - off] : 0;
        __syncthreads();
        if (tid < BNODES) snc[tid] += t;
        __syncthreads();
    }
    int excl = (tid < BNODES) ? snc[tid] - ncnt[tid] : 0;
    if (tid < BNODES && gn < N) offsets[gn] = rlo + excl;
    if (b == 0 && tid == 0) offsets[N] = E;
    __syncthreads();
    if (tid < BNODES) ncnt[tid] = excl;   // relative cursor
    __syncthreads();

    for (int r = rlo + tid; r < rhi; r += 256) {
        uint2 rec = recs[r];
        int dl = (int)(rec.y & (BNODES - 1u));
        unsigned s = rec.y >> BSHIFT;
        int slot = rlo + atomicAdd(&ncnt[dl], 1);
        csr[slot] = make_uint2(rec.x, s);   // (edge, src)
    }
}

// ---------------- K5: fused score + aggregation ----------------
// block = 256 = 4 independent waves, one dst node per wave. No LDS, no
// __syncthreads. Staging role (j=lane>>3, hh=lane&7): ex for 8 edges x 8 heads
// in registers; inner role (h=lane>>3, fp=lane&7): unrolled 8-edge body with
// __shfl broadcast of ex / src -> 8 independent half2 gathers in flight.
__global__ __launch_bounds__(256) void agg_kernel(
    const uint2* __restrict__ csr, const int* __restrict__ offsets,
    const float* __restrict__ post, const float* __restrict__ eps,
    const __half* __restrict__ hbuf, const float* __restrict__ bias,
    float* __restrict__ out, int N)
{
    const int lane = threadIdx.x & 63;
    const int d = blockIdx.x * 4 + (threadIdx.x >> 6);
    if (d >= N) return;
    const int start = offsets[d];
    const int deg = offsets[d + 1] - start;
    const int j = lane >> 3, hh = lane & 7;   // staging role
    const int h = j;                          // inner role head (same bits)
    const float dl  = post[d * 32 + 8 + hh];   // loc_r[d][hh]
    const float dls = post[d * 32 + 24 + hh];  // lsr[d][hh]

    float2 acc = make_float2(0.f, 0.f);
    float dsum = 0.f;

    int c = 0;
    for (; c + 8 <= deg; c += 8) {
        uint2 rec = csr[start + c + j];
        int e = (int)rec.x, s = (int)rec.y;
        float ll = post[s * 32 + hh];
        float sl = post[s * 32 + 16 + hh];
        float ep = eps[(size_t)e * 8 + hh];
        float ex = __expf((ll + dl) + __expf(sl + dls) * ep);
#pragma unroll
        for (int jj = 0; jj < 8; ++jj) {
            float a = __shfl(ex, jj * 8 + h, 64);
            int  sj = __shfl(s, jj * 8, 64);
            float2 hv = __half22float2(((const __half2*)(hbuf + (size_t)sj * HF))[lane]);
            acc.x += a * hv.x;
            acc.y += a * hv.y;
            dsum += a;
        }
    }
    if (c < deg) {
        int jc = deg - c;
        uint2 rec = csr[start + c + min(j, jc - 1)];
        int e = (int)rec.x, s = (int)rec.y;
        float ll = post[s * 32 + hh];
        float sl = post[s * 32 + 16 + hh];
        float ep = eps[(size_t)e * 8 + hh];
        float ex = (j < jc) ? __expf((ll + dl) + __expf(sl + dls) * ep) : 0.f;
        for (int jj = 0; jj < jc; ++jj) {
            float a = __shfl(ex, jj * 8 + h, 64);
            int  sj = __shfl(s, jj * 8, 64);
            float2 hv = __half22float2(((const __half2*)(hbuf + (size_t)sj * HF))[lane]);
            acc.x += a * hv.x;
            acc.y += a * hv.y;
            dsum += a;
        }
    }

    float inv = (dsum > 0.f) ? 1.f / dsum : 0.f;
    float2 bv = ((const float2*)bias)[lane];          // bias[h*16 + 2fp .. +1]
    float2 o = make_float2(acc.x * inv + bv.x, acc.y * inv + bv.y);
    ((float2*)out)[(size_t)d * 64 + lane] = o;
}

extern "C" void kernel_launch(void* const* d_in, const int* in_sizes, int n_in,
                              void* d_out, int out_size, void* d_ws, size_t ws_size,
                              hipStream_t stream)
{
    const float* feat   = (const float*)d_in[0];
    const int*   src    = (const int*)d_in[1];
    const int*   dst    = (const int*)d_in[2];
    const float* eps    = (const float*)d_in[3];
    const float* W_fc   = (const float*)d_in[4];
    const float* W_post = (const float*)d_in[5];
    const float* b_post = (const float*)d_in[6];
    const float* bias   = (const float*)d_in[7];
    float* out = (float*)d_out;

    const int N = in_sizes[0] / IN_FEAT;         // 50000
    const int E = in_sizes[1];                   // 1600000
    const int nb = (N + BNODES - 1) >> BSHIFT;   // 782 buckets
    const int SB = (E + CHUNK - 1) / CHUNK;      // scatter blocks (391)
    const int GB = (N + 31) / 32;                // gemm blocks (1563)

    // workspace layout (256B-aligned segments), total ~45 MB
    char* p = (char*)d_ws;
    auto alloc = [&](size_t bytes) {
        char* r = p;
        p += (bytes + 255) & ~size_t(255);
        return r;
    };
    __half* hbuf    = (__half*)alloc((size_t)N * HF * 2);     // 12.8 MB fp16
    float*  post    = (float*)alloc((size_t)N * 32 * 4);      // 6.4 MB
    int*    offsets = (int*)alloc((size_t)(N + 1) * 4);
    int*    bucket_tot    = (int*)alloc((size_t)(NBMAX + 1) * 4);
    int*    bucket_base   = (int*)alloc((size_t)(NBMAX + 1) * 4);
    int*    bucket_cursor = (int*)alloc((size_t)(NBMAX + 1) * 4);
    uint2*  recs    = (uint2*)alloc((size_t)E * 8);           // 12.8 MB
    uint2*  csr     = (uint2*)alloc((size_t)E * 8);           // 12.8 MB (edge, src)

    hipMemsetAsync(bucket_tot, 0, (size_t)nb * 4, stream);

    bucket_hist_kernel<<<512, 256, 0, stream>>>(dst, bucket_tot, E, nb);
    bucket_scan_kernel<<<1, 256, 0, stream>>>(bucket_tot, bucket_base,
                                              bucket_cursor, nb, E);
    gemm_scatter_kernel<<<SB + GB, 256, 0, stream>>>(
        feat, W_fc, W_post, b_post, hbuf, post, N,
        src, dst, bucket_cursor, recs, E, nb, SB);
    bucket_csr_kernel<<<nb, 256, 0, stream>>>(recs, bucket_base, offsets, csr, N, E);
    agg_kernel<<<(N + 3) / 4, 256, 0, stream>>>(csr, offsets, post, eps, hbuf,
                                                bias, out, N);
}